// Round 1
// baseline (494.102 us; speedup 1.0000x reference)
//
#include <hip/hip_runtime.h>
#include <math.h>

// Problem constants
constexpr int TT = 4;
constexpr int BB = 32;
constexpr int CC = 384;
constexpr int NN = 256;      // H*W
constexpr int HEADS = 8;
constexpr int HD = 48;
constexpr int BCN = BB * CC * NN;      // 3,145,728
constexpr int TBCN = TT * BCN;         // 12,582,912

// GEMM tiles
constexpr int OT = 64;
constexpr int NT = 64;
constexpr int KT = 32;

// ---------------------------------------------------------------------------
// Kernel 1: shortcut LIF on x -> u8 spikes xs, layout [T,B,C,N]
// ---------------------------------------------------------------------------
__global__ __launch_bounds__(256) void k_lif_x(const float* __restrict__ x,
                                               unsigned char* __restrict__ xs) {
    int i4 = blockIdx.x * 256 + threadIdx.x;   // each thread: 4 consecutive elems
    if (i4 >= BCN / 4) return;
    size_t base = (size_t)i4 * 4;
    float v0 = 0.f, v1 = 0.f, v2 = 0.f, v3 = 0.f;
#pragma unroll
    for (int t = 0; t < TT; ++t) {
        float4 xt = *(const float4*)(x + (size_t)t * BCN + base);
        uchar4 s;
        v0 += (xt.x - v0) * 0.5f; s.x = (v0 >= 0.5f); if (s.x) v0 = 0.f;
        v1 += (xt.y - v1) * 0.5f; s.y = (v1 >= 0.5f); if (s.y) v1 = 0.f;
        v2 += (xt.z - v2) * 0.5f; s.z = (v2 >= 0.5f); if (s.z) v2 = 0.f;
        v3 += (xt.w - v3) * 0.5f; s.w = (v3 >= 0.5f); if (s.w) v3 = 0.f;
        *(uchar4*)(xs + (size_t)t * BCN + base) = s;
    }
}

// ---------------------------------------------------------------------------
// Kernel 2: branch = conv1x1(xs, w) + BN + LIF -> u8 spikes [T,B,C,N]
// If vout != nullptr, also write spikes as f32 in [T,B,heads,N,hd] layout.
// Block: 256 threads, each owns 4o x 4n x all 4 t. Grid (B, C/OT, N/NT).
// ---------------------------------------------------------------------------
__global__ __launch_bounds__(256) void k_branch(
    const unsigned char* __restrict__ xs, const float* __restrict__ w,
    const float* __restrict__ gg, const float* __restrict__ bb,
    const float* __restrict__ mm, const float* __restrict__ vv,
    unsigned char* __restrict__ spk, float* __restrict__ vout) {
    __shared__ __align__(16) float sX[TT][KT][NT];
    __shared__ __align__(16) float sW[KT][OT + 4];

    const int b  = blockIdx.x;
    const int ob = blockIdx.y * OT;
    const int nb = blockIdx.z * NT;
    const int tid = threadIdx.x;
    const int ti = tid & 15, tj = tid >> 4;
    const int n0 = ti * 4, o0 = tj * 4;

    float acc[TT][4][4];
#pragma unroll
    for (int t = 0; t < TT; ++t)
#pragma unroll
        for (int i = 0; i < 4; ++i)
#pragma unroll
            for (int j = 0; j < 4; ++j) acc[t][i][j] = 0.f;

    for (int k0 = 0; k0 < CC; k0 += KT) {
        // stage W tile [KT][OT]
#pragma unroll
        for (int i = 0; i < (OT * KT) / 256; ++i) {
            int e = tid + i * 256;
            int o = e >> 5, k = e & 31;
            sW[k][o] = w[(ob + o) * CC + k0 + k];
        }
        // stage X tile [T][KT][NT] (u8 -> f32)
#pragma unroll
        for (int i = 0; i < (TT * KT * NT / 4) / 256; ++i) {
            int e = tid + i * 256;
            int n4 = e & 15, k = (e >> 4) & 31, t = e >> 9;
            uchar4 u = *(const uchar4*)(xs + ((size_t)((t * BB + b) * CC) + k0 + k) * NN + nb + n4 * 4);
            float* d = &sX[t][k][n4 * 4];
            d[0] = u.x; d[1] = u.y; d[2] = u.z; d[3] = u.w;
        }
        __syncthreads();
#pragma unroll
        for (int k = 0; k < KT; ++k) {
            float4 wv4 = *(const float4*)&sW[k][o0];
            float wa[4] = {wv4.x, wv4.y, wv4.z, wv4.w};
#pragma unroll
            for (int t = 0; t < TT; ++t) {
                float4 xv4 = *(const float4*)&sX[t][k][n0];
                float xa[4] = {xv4.x, xv4.y, xv4.z, xv4.w};
#pragma unroll
                for (int i = 0; i < 4; ++i)
#pragma unroll
                    for (int j = 0; j < 4; ++j)
                        acc[t][i][j] = fmaf(wa[i], xa[j], acc[t][i][j]);
            }
        }
        __syncthreads();
    }

    // epilogue: BN + LIF, write spikes
#pragma unroll
    for (int i = 0; i < 4; ++i) {
        const int o = ob + o0 + i;
        const float inv = gg[o] / sqrtf(vv[o] + 1e-5f);
        const float m4 = mm[o], b4 = bb[o];
        const int h = o / HD, d = o % HD;
        float vm[4] = {0.f, 0.f, 0.f, 0.f};
#pragma unroll
        for (int t = 0; t < TT; ++t) {
            uchar4 s4;
            unsigned char* sp = (unsigned char*)&s4;
#pragma unroll
            for (int j = 0; j < 4; ++j) {
                float y = (acc[t][i][j] - m4) * inv + b4;
                vm[j] += (y - vm[j]) * 0.5f;
                int s = (vm[j] >= 0.5f);
                sp[j] = (unsigned char)s;
                if (s) vm[j] = 0.f;
            }
            *(uchar4*)(spk + ((size_t)((t * BB + b) * CC) + o) * NN + nb + n0) = s4;
            if (vout) {
                size_t vb = ((size_t)((t * BB + b) * HEADS + h) * NN) * HD;
#pragma unroll
                for (int j = 0; j < 4; ++j)
                    vout[vb + (size_t)(nb + n0 + j) * HD + d] = (float)sp[j];
            }
        }
    }
}

// ---------------------------------------------------------------------------
// Kernel 3: kv = sum_n k*v per (t,b,c); talking heads 8x8; LIF over T.
// One block per b. Writes kv spikes u8 in [t,b,c] (c = o*HD+d).
// ---------------------------------------------------------------------------
__global__ __launch_bounds__(256) void k_kv(const unsigned char* __restrict__ ks,
                                            const unsigned char* __restrict__ vs,
                                            const float* __restrict__ th,
                                            unsigned char* __restrict__ kvs) {
    __shared__ float kv0[TT][HEADS * HD];
    const int b = blockIdx.x, tid = threadIdx.x;
    for (int e = tid; e < TT * HEADS * HD; e += 256) {
        int t = e / (HEADS * HD), c = e % (HEADS * HD);
        const uchar4* kp = (const uchar4*)(ks + ((size_t)((t * BB + b) * CC) + c) * NN);
        const uchar4* vp = (const uchar4*)(vs + ((size_t)((t * BB + b) * CC) + c) * NN);
        int sum = 0;
        for (int i = 0; i < NN / 4; ++i) {
            uchar4 a = kp[i], c4 = vp[i];
            sum += a.x * c4.x + a.y * c4.y + a.z * c4.z + a.w * c4.w;
        }
        kv0[t][c] = (float)sum;
    }
    __syncthreads();
    for (int e = tid; e < HEADS * HD; e += 256) {
        int o = e / HD, d = e % HD;
        float vm = 0.f;
#pragma unroll
        for (int t = 0; t < TT; ++t) {
            float s = 0.f;
#pragma unroll
            for (int h = 0; h < HEADS; ++h) s += th[o * HEADS + h] * kv0[t][h * HD + d];
            vm += (s - vm) * 0.5f;
            int sp = (vm >= 0.5f);
            if (sp) vm = 0.f;
            kvs[(size_t)((t * BB + b) * CC) + o * HD + d] = (unsigned char)sp;
        }
    }
}

// ---------------------------------------------------------------------------
// Kernel 4: x_att = q * kv_mask; out = bn(conv1x1(x_att, pw) + pbias) + x
// Same tiling as k_branch; mask folded into LDS staging.
// ---------------------------------------------------------------------------
__global__ __launch_bounds__(256) void k_proj(
    const unsigned char* __restrict__ qs, const unsigned char* __restrict__ kvs,
    const float* __restrict__ w, const float* __restrict__ pbias,
    const float* __restrict__ gg, const float* __restrict__ bb,
    const float* __restrict__ mm, const float* __restrict__ vv,
    const float* __restrict__ xin, float* __restrict__ out) {
    __shared__ __align__(16) float sX[TT][KT][NT];
    __shared__ __align__(16) float sW[KT][OT + 4];

    const int b  = blockIdx.x;
    const int ob = blockIdx.y * OT;
    const int nb = blockIdx.z * NT;
    const int tid = threadIdx.x;
    const int ti = tid & 15, tj = tid >> 4;
    const int n0 = ti * 4, o0 = tj * 4;

    float acc[TT][4][4];
#pragma unroll
    for (int t = 0; t < TT; ++t)
#pragma unroll
        for (int i = 0; i < 4; ++i)
#pragma unroll
            for (int j = 0; j < 4; ++j) acc[t][i][j] = 0.f;

    for (int k0 = 0; k0 < CC; k0 += KT) {
#pragma unroll
        for (int i = 0; i < (OT * KT) / 256; ++i) {
            int e = tid + i * 256;
            int o = e >> 5, k = e & 31;
            sW[k][o] = w[(ob + o) * CC + k0 + k];
        }
#pragma unroll
        for (int i = 0; i < (TT * KT * NT / 4) / 256; ++i) {
            int e = tid + i * 256;
            int n4 = e & 15, k = (e >> 4) & 31, t = e >> 9;
            float mk = (float)kvs[(size_t)((t * BB + b) * CC) + k0 + k];
            uchar4 u = *(const uchar4*)(qs + ((size_t)((t * BB + b) * CC) + k0 + k) * NN + nb + n4 * 4);
            float* d = &sX[t][k][n4 * 4];
            d[0] = mk * u.x; d[1] = mk * u.y; d[2] = mk * u.z; d[3] = mk * u.w;
        }
        __syncthreads();
#pragma unroll
        for (int k = 0; k < KT; ++k) {
            float4 wv4 = *(const float4*)&sW[k][o0];
            float wa[4] = {wv4.x, wv4.y, wv4.z, wv4.w};
#pragma unroll
            for (int t = 0; t < TT; ++t) {
                float4 xv4 = *(const float4*)&sX[t][k][n0];
                float xa[4] = {xv4.x, xv4.y, xv4.z, xv4.w};
#pragma unroll
                for (int i = 0; i < 4; ++i)
#pragma unroll
                    for (int j = 0; j < 4; ++j)
                        acc[t][i][j] = fmaf(wa[i], xa[j], acc[t][i][j]);
            }
        }
        __syncthreads();
    }

#pragma unroll
    for (int i = 0; i < 4; ++i) {
        const int o = ob + o0 + i;
        const float inv = gg[o] / sqrtf(vv[o] + 1e-5f);
        const float m4 = mm[o], b4 = bb[o], pb = pbias[o];
#pragma unroll
        for (int t = 0; t < TT; ++t) {
            size_t idx = ((size_t)((t * BB + b) * CC) + o) * NN + nb + n0;
            float4 xid = *(const float4*)(xin + idx);
            float4 r;
            r.x = (acc[t][i][0] + pb - m4) * inv + b4 + xid.x;
            r.y = (acc[t][i][1] + pb - m4) * inv + b4 + xid.y;
            r.z = (acc[t][i][2] + pb - m4) * inv + b4 + xid.z;
            r.w = (acc[t][i][3] + pb - m4) * inv + b4 + xid.w;
            *(float4*)(out + idx) = r;
        }
    }
}

// ---------------------------------------------------------------------------
extern "C" void kernel_launch(void* const* d_in, const int* in_sizes, int n_in,
                              void* d_out, int out_size, void* d_ws, size_t ws_size,
                              hipStream_t stream) {
    const float* x    = (const float*)d_in[0];
    const float* q_w  = (const float*)d_in[1];
    const float* k_w  = (const float*)d_in[2];
    const float* v_w  = (const float*)d_in[3];
    const float* q_g  = (const float*)d_in[4];
    const float* q_b  = (const float*)d_in[5];
    const float* q_m  = (const float*)d_in[6];
    const float* q_v  = (const float*)d_in[7];
    const float* k_g  = (const float*)d_in[8];
    const float* k_b  = (const float*)d_in[9];
    const float* k_m  = (const float*)d_in[10];
    const float* k_v  = (const float*)d_in[11];
    const float* v_g  = (const float*)d_in[12];
    const float* v_b  = (const float*)d_in[13];
    const float* v_m  = (const float*)d_in[14];
    const float* v_v  = (const float*)d_in[15];
    const float* p_g  = (const float*)d_in[16];
    const float* p_b  = (const float*)d_in[17];
    const float* p_m  = (const float*)d_in[18];
    const float* p_v  = (const float*)d_in[19];
    const float* th_w = (const float*)d_in[20];
    const float* pr_w = (const float*)d_in[21];
    const float* pr_b = (const float*)d_in[22];

    float* out  = (float*)d_out;          // x_out [T,B,C,H,W]
    float* vout = out + TBCN;             // v spikes [T,B,heads,N,hd]

    unsigned char* ws  = (unsigned char*)d_ws;
    unsigned char* xs  = ws;                       // TBCN bytes
    unsigned char* qs  = ws + (size_t)TBCN;        // TBCN
    unsigned char* ks2 = ws + (size_t)2 * TBCN;    // TBCN
    unsigned char* vs2 = ws + (size_t)3 * TBCN;    // TBCN
    unsigned char* kvs = ws + (size_t)4 * TBCN;    // T*B*C bytes

    k_lif_x<<<(BCN / 4) / 256, 256, 0, stream>>>(x, xs);

    dim3 gg(BB, CC / OT, NN / NT);
    k_branch<<<gg, 256, 0, stream>>>(xs, q_w, q_g, q_b, q_m, q_v, qs, nullptr);
    k_branch<<<gg, 256, 0, stream>>>(xs, k_w, k_g, k_b, k_m, k_v, ks2, nullptr);
    k_branch<<<gg, 256, 0, stream>>>(xs, v_w, v_g, v_b, v_m, v_v, vs2, vout);

    k_kv<<<BB, 256, 0, stream>>>(ks2, vs2, th_w, kvs);

    k_proj<<<gg, 256, 0, stream>>>(qs, kvs, pr_w, pr_b, p_g, p_b, p_m, p_v, x, out);
}